// Round 5
// baseline (25.787 us; speedup 1.0000x reference)
//
#include <hip/hip_runtime.h>

// Multi-head embedding gather:
//   out[b,s,h,:] = weight[hash_ids[b,s,h] + offsets[h], :]
// B=4, S=4096, H=8, DIM=128 (fp32). Output rows = 131072.
// Memory-bound. 32 lanes x float4 = 512 B per row.
// Cached loads (L2 dedups ~8% repeated rows), NT stores (write-once
// stream stays out of L2). This round: 4 rows per 32-lane group for
// 4x memory-level parallelism on the random read stream + 2 KB
// contiguous write bursts.

typedef float f32x4 __attribute__((ext_vector_type(4)));

constexpr int DIM = 128;
constexpr int NHEADS = 8;
constexpr int ROWS_PER_GROUP = 4;

__global__ __launch_bounds__(256) void OffloadMultiHeadEmbedding_kernel(
    const int* __restrict__ hash_ids,   // [R] flattened (B*S*H), innermost = head
    const float* __restrict__ weight,   // [TOTAL, DIM]
    const int* __restrict__ offsets,    // [NHEADS]
    float* __restrict__ out,            // [R, DIM]
    int nrows)
{
    int t = blockIdx.x * blockDim.x + threadIdx.x;
    int g = t >> 5;                     // 32-lane group id
    int lane = t & 31;
    int row0 = g * ROWS_PER_GROUP;
    if (row0 >= nrows) return;

    // one vectorized index load for 4 consecutive rows (row0 % 4 == 0)
    int4 id4 = *reinterpret_cast<const int4*>(hash_ids + row0);
    int ids[ROWS_PER_GROUP] = {id4.x, id4.y, id4.z, id4.w};

    // issue all 4 independent row loads before any store (MLP)
    f32x4 v[ROWS_PER_GROUP];
#pragma unroll
    for (int i = 0; i < ROWS_PER_GROUP; ++i) {
        int r = row0 + i;
        int h = r & (NHEADS - 1);
        long gid = (long)ids[i] + (long)offsets[h];
        v[i] = *(reinterpret_cast<const f32x4*>(weight + (size_t)gid * DIM) + lane);
    }

#pragma unroll
    for (int i = 0; i < ROWS_PER_GROUP; ++i) {
        __builtin_nontemporal_store(
            v[i], reinterpret_cast<f32x4*>(out + (size_t)(row0 + i) * DIM) + lane);
    }
}

extern "C" void kernel_launch(void* const* d_in, const int* in_sizes, int n_in,
                              void* d_out, int out_size, void* d_ws, size_t ws_size,
                              hipStream_t stream) {
    const int*   hash_ids = (const int*)d_in[0];    // [B*S*H]
    const float* weight   = (const float*)d_in[1];  // [TOTAL, DIM]
    const int*   offsets  = (const int*)d_in[2];    // [NHEADS]
    float*       out      = (float*)d_out;

    int nrows = in_sizes[0];                        // 131072
    int ngroups = (nrows + ROWS_PER_GROUP - 1) / ROWS_PER_GROUP;
    int total_threads = ngroups * 32;
    int block = 256;
    int grid = (total_threads + block - 1) / block;

    OffloadMultiHeadEmbedding_kernel<<<grid, block, 0, stream>>>(
        hash_ids, weight, offsets, out, nrows);
}

// Round 6
// 25.686 us; speedup vs baseline: 1.0039x; 1.0039x over previous
//
#include <hip/hip_runtime.h>

// Multi-head embedding gather:
//   out[b,s,h,:] = weight[hash_ids[b,s,h] + offsets[h], :]
// B=4, S=4096, H=8, DIM=128 (fp32). Output rows = 131072.
// Memory-bound. 32 lanes x float4 = 512 B per row.
// Cached loads (L2 dedups ~8% repeated rows), NT stores (write-once
// stream stays out of L2). ROWS_PER_GROUP=2: vectorized index load +
// 2-deep read MLP per thread, without R5's 4x wave-count reduction.

typedef float f32x4 __attribute__((ext_vector_type(4)));

constexpr int DIM = 128;
constexpr int NHEADS = 8;
constexpr int ROWS_PER_GROUP = 2;

__global__ __launch_bounds__(256) void OffloadMultiHeadEmbedding_kernel(
    const int* __restrict__ hash_ids,   // [R] flattened (B*S*H), innermost = head
    const float* __restrict__ weight,   // [TOTAL, DIM]
    const int* __restrict__ offsets,    // [NHEADS]
    float* __restrict__ out,            // [R, DIM]
    int nrows)
{
    int t = blockIdx.x * blockDim.x + threadIdx.x;
    int g = t >> 5;                     // 32-lane group id
    int lane = t & 31;
    int row0 = g * ROWS_PER_GROUP;
    if (row0 >= nrows) return;

    // one vectorized index load for 2 consecutive rows (row0 % 2 == 0)
    int2 id2 = *reinterpret_cast<const int2*>(hash_ids + row0);
    int ids[ROWS_PER_GROUP] = {id2.x, id2.y};

    // issue both independent row loads before any store (MLP)
    f32x4 v[ROWS_PER_GROUP];
#pragma unroll
    for (int i = 0; i < ROWS_PER_GROUP; ++i) {
        int r = row0 + i;
        int h = r & (NHEADS - 1);
        long gid = (long)ids[i] + (long)offsets[h];
        v[i] = *(reinterpret_cast<const f32x4*>(weight + (size_t)gid * DIM) + lane);
    }

#pragma unroll
    for (int i = 0; i < ROWS_PER_GROUP; ++i) {
        __builtin_nontemporal_store(
            v[i], reinterpret_cast<f32x4*>(out + (size_t)(row0 + i) * DIM) + lane);
    }
}

extern "C" void kernel_launch(void* const* d_in, const int* in_sizes, int n_in,
                              void* d_out, int out_size, void* d_ws, size_t ws_size,
                              hipStream_t stream) {
    const int*   hash_ids = (const int*)d_in[0];    // [B*S*H]
    const float* weight   = (const float*)d_in[1];  // [TOTAL, DIM]
    const int*   offsets  = (const int*)d_in[2];    // [NHEADS]
    float*       out      = (float*)d_out;

    int nrows = in_sizes[0];                        // 131072
    int ngroups = (nrows + ROWS_PER_GROUP - 1) / ROWS_PER_GROUP;
    int total_threads = ngroups * 32;
    int block = 256;
    int grid = (total_threads + block - 1) / block;

    OffloadMultiHeadEmbedding_kernel<<<grid, block, 0, stream>>>(
        hash_ids, weight, offsets, out, nrows);
}